// Round 14
// baseline (175.842 us; speedup 1.0000x reference)
//
#include <hip/hip_runtime.h>
#include <hip/hip_bf16.h>
#include <hip/hip_fp16.h>

#define BATCH_N 256
#define IN_F    16384
#define OUT_F   16384
#define NXCD    8
#define CAPX    32               // slots per (row,xcd) sub-bin; Poisson(7.6) + ~10 sigma
#define EPB     2048             // edges per scatter block (489 blocks)
#define TBLK    1024             // transpose blocks inside fused prep kernel

typedef unsigned int u32x4 __attribute__((ext_vector_type(4)));
typedef float f32x4 __attribute__((ext_vector_type(4)));

// actual XCD id of the CU this block runs on [measured: learn_hip m09]
__device__ inline int get_xcc() {
    unsigned int x;
    asm volatile("s_getreg_b32 %0, hwreg(HW_REG_XCC_ID)" : "=s"(x));
    return (int)(x & 7);
}

// ---------------- fused prep: transpose_x (blocks 0..1023) + direct scatter ----------------
// Scatter writes final 4 B records (col<<16 | fp16(val)) straight into
// edges[row][xcd][CAPX]. Sub-bin (128 B) and cursor lines are single-XCD-writer
// by construction -> no cross-XCD RMW bounce. edges/cursor pre-zeroed by memset.

__global__ void prep_kernel(const float* __restrict__ x,
                            __hip_bfloat16* __restrict__ xTh,
                            const int* __restrict__ rows,
                            const int* __restrict__ cols,
                            const float* __restrict__ vals, int nnz,
                            int* __restrict__ cursor,          // [NXCD][OUT_F]
                            unsigned int* __restrict__ edges) { // [OUT][NXCD][CAPX]
    __shared__ float tile[64 * 65];
    int t = threadIdx.x;
    if (blockIdx.x < TBLK) {
        // ---- transpose + bf16 quantize: x [256][IN] -> xTh [2][IN][128] ----
        int bid = blockIdx.x;
        int i0 = (bid & 255) * 64;
        int b0 = (bid >> 8) * 64;
        int tx4 = t & 15;
        int r16 = t >> 4;
#pragma unroll
        for (int k = 0; k < 4; ++k) {
            int row = r16 + k * 16;
            f32x4 v = *(const f32x4*)(x + (size_t)(b0 + row) * IN_F + i0 + tx4 * 4);
            tile[row * 65 + tx4 * 4 + 0] = v.x;
            tile[row * 65 + tx4 * 4 + 1] = v.y;
            tile[row * 65 + tx4 * 4 + 2] = v.z;
            tile[row * 65 + tx4 * 4 + 3] = v.w;
        }
        __syncthreads();
        int tx = t & 63, ty = t >> 6;
        int h = b0 >> 7, j0 = b0 & 127;
#pragma unroll
        for (int k = 0; k < 64; k += 4) {
            int col = i0 + ty + k;
            xTh[((size_t)h * IN_F + col) * 128 + j0 + tx] =
                __float2bfloat16(tile[tx * 65 + ty + k]);
        }
    } else {
        // ---- direct scatter of 2048 edges into per-(row,XCD) sub-bins ----
        int sub = get_xcc();
        int* cur = cursor + sub * OUT_F;
        int i0 = (blockIdx.x - TBLK) * EPB;
#pragma unroll
        for (int k = 0; k < 8; ++k) {
            int i = i0 + k * 256 + t;
            if (i < nnz) {
                int r = rows[i];
                unsigned int c = (unsigned int)cols[i];
                __half hv = __float2half(vals[i]);
                unsigned int rec = (c << 16) | (unsigned int)__half_as_ushort(hv);
                int pos = atomicAdd(&cur[r], 1);
                if (pos < CAPX)
                    edges[((size_t)r * NXCD + sub) * CAPX + pos] = rec;
            }
        }
    }
}

// ---------------- accumulate + direct transposed output ----------------
// 2048 blocks: rowgroup = blk>>1 (16 rows), h = blk&1 (round-robin XCD dispatch
// keeps one 4 MB xh half per XCD L2). Per row: 8 scalar sub-lists (zero-padded
// by the memset, so tail records contribute exactly 0). LDS slab; final out
// written directly (16 floats = one 64 B line per store).

__global__ void accum_kernel(const unsigned int* __restrict__ xh0, // [2][IN][64] bf162
                             const unsigned int* __restrict__ edges, // [OUT][NXCD][CAPX]
                             const int*   __restrict__ cursor,    // [NXCD][OUT_F]
                             const float* __restrict__ bias,
                             float* __restrict__ out) {            // [256][OUT]
    __shared__ float slab[128][17];     // [batch_in_half][row_local], pad 17
    int blk = blockIdx.x;
    int h = blk & 1;
    int o0 = (blk >> 1) * 16;
    int w = threadIdx.x >> 6;           // wave 0..3
    int lane = threadIdx.x & 63;
    const unsigned int* xh = xh0 + (size_t)h * IN_F * 64;
#pragma unroll
    for (int rr = 0; rr < 4; ++rr) {
        int rl = w * 4 + rr;
        int o = __builtin_amdgcn_readfirstlane(o0 + rl);
        const unsigned int* re = edges + (size_t)o * (NXCD * CAPX);
        float ax = 0.f, ay = 0.f;
        for (int sub = 0; sub < NXCD; ++sub) {
            int n = cursor[sub * OUT_F + o];     // uniform
            if (n > CAPX) n = CAPX;
            const unsigned int* el = re + sub * CAPX;
            for (int j = 0; j < n; j += 8) {     // reads past n are zero records
                unsigned int e[8];
#pragma unroll
                for (int k = 0; k < 8; ++k) e[k] = el[j + k];   // uniform -> s_load
                unsigned int g[8];
#pragma unroll
                for (int k = 0; k < 8; ++k) {
                    const unsigned int* p = xh + ((e[k] >> 16) << 6);  // scalar base
                    g[k] = p[lane];                                     // vgpr offset
                }
#pragma unroll
                for (int k = 0; k < 8; ++k) {
                    float v = __half2float(__ushort_as_half((unsigned short)(e[k] & 0xffffu)));
                    ax += __uint_as_float(g[k] << 16) * v;
                    ay += __uint_as_float(g[k] & 0xffff0000u) * v;
                }
            }
        }
        float bv = bias[o];
        slab[2 * lane + 0][rl] = ax + bv;   // batch 2t   of this half
        slab[2 * lane + 1][rl] = ay + bv;   // batch 2t+1
    }
    __syncthreads();
    // write phase: 512 float4 items (128 batches x 4 quarters), 2 per thread
#pragma unroll
    for (int it = 0; it < 2; ++it) {
        int item = threadIdx.x + it * 256;
        int bl = item >> 2;             // batch within half, 0..127
        int q = item & 3;               // quarter of 16 rows
        f32x4 v;
        v.x = slab[bl][q * 4 + 0];
        v.y = slab[bl][q * 4 + 1];
        v.z = slab[bl][q * 4 + 2];
        v.w = slab[bl][q * 4 + 3];
        __builtin_nontemporal_store(v,
            (f32x4*)(out + (size_t)(h * 128 + bl) * OUT_F + o0 + q * 4));
    }
}

extern "C" void kernel_launch(void* const* d_in, const int* in_sizes, int n_in,
                              void* d_out, int out_size, void* d_ws, size_t ws_size,
                              hipStream_t stream) {
    const float* x     = (const float*)d_in[0];
    const float* wvals = (const float*)d_in[1];
    const float* bias  = (const float*)d_in[2];
    const int*   rows  = (const int*)d_in[3];
    const int*   cols  = (const int*)d_in[4];
    float* out = (float*)d_out;
    int nnz = in_sizes[1];

    const size_t MB = 1024 * 1024;
    char* ws = (char*)d_ws;
    __hip_bfloat16* xTh = (__hip_bfloat16*)(ws);        // [0, 8 MB): [2][IN][128] bf16
    int* cursor = (int*)(ws + 8 * MB);                  // 512 KB: [NXCD][OUT_F]
    unsigned int* edges = (unsigned int*)(ws + 9 * MB); // 16 MB: [OUT][NXCD][CAPX]

    // zero cursors + edges in one fill (zero records contribute 0 in accum)
    (void)hipMemsetAsync(ws + 8 * MB, 0, 17 * MB, stream);

    int npart = (nnz + EPB - 1) / EPB;
    prep_kernel<<<TBLK + npart, 256, 0, stream>>>(x, xTh, rows, cols, wvals, nnz,
                                                  cursor, edges);
    accum_kernel<<<(OUT_F / 16) * 2, 256, 0, stream>>>((const unsigned int*)xTh, edges,
                                                       cursor, bias, out);
}

// Round 15
// 141.308 us; speedup vs baseline: 1.2444x; 1.2444x over previous
//
#include <hip/hip_runtime.h>
#include <hip/hip_bf16.h>
#include <hip/hip_fp16.h>

#define BATCH_N 256
#define IN_F    16384
#define OUT_F   16384
#define CAP     128              // edge slots per row (mean 61, 8.6 sigma margin)
#define NBUCK   512              // coarse buckets: row >> 5, 32 rows each
#define CAPB    2560             // bucket staging capacity (mean 1953 + 13 sigma)
#define EPB     2048             // edges per partition block (489 blocks)
#define TBLK    1024             // transpose blocks inside fused prep kernel

typedef unsigned int u32x4 __attribute__((ext_vector_type(4)));
typedef float f32x4 __attribute__((ext_vector_type(4)));

// ---------------- fused prep: transpose_x (blocks 0..1023) + partition ----------------
// staging record: x = (row<<14)|col, y = fp32 bits of val. Exact reservations.

__global__ void prep_kernel(const float* __restrict__ x,
                            __hip_bfloat16* __restrict__ xTh,
                            const int* __restrict__ rows,
                            const int* __restrict__ cols,
                            const float* __restrict__ vals, int nnz,
                            int* __restrict__ gcursor,
                            uint2* __restrict__ staging) {
    __shared__ int smem[64 * 65];      // transpose tile / partition hist+base
    int t = threadIdx.x;
    if (blockIdx.x < TBLK) {
        // ---- transpose + bf16 quantize: x [256][IN] -> xTh [2][IN][128] ----
        float* tile = (float*)smem;        // [64][65]
        int bid = blockIdx.x;
        int i0 = (bid & 255) * 64;
        int b0 = (bid >> 8) * 64;
        int tx4 = t & 15;                  // float4 index within 64-col tile
        int r16 = t >> 4;                  // 0..15
#pragma unroll
        for (int k = 0; k < 4; ++k) {
            int row = r16 + k * 16;        // batch row within tile
            f32x4 v = *(const f32x4*)(x + (size_t)(b0 + row) * IN_F + i0 + tx4 * 4);
            tile[row * 65 + tx4 * 4 + 0] = v.x;
            tile[row * 65 + tx4 * 4 + 1] = v.y;
            tile[row * 65 + tx4 * 4 + 2] = v.z;
            tile[row * 65 + tx4 * 4 + 3] = v.w;
        }
        __syncthreads();
        int tx = t & 63, ty = t >> 6;
        int h = b0 >> 7, j0 = b0 & 127;
#pragma unroll
        for (int k = 0; k < 64; k += 4) {
            int col = i0 + ty + k;
            xTh[((size_t)h * IN_F + col) * 128 + j0 + tx] =
                __float2bfloat16(tile[tx * 65 + ty + k]);
        }
    } else {
        // ---- partition 2048 edges into 512 coarse buckets ----
        int* hist = smem;                  // [512]
        int* base = smem + NBUCK;          // [512]
        hist[t] = 0; hist[t + 256] = 0;
        __syncthreads();
        int i0 = (blockIdx.x - TBLK) * EPB;
        unsigned int pack[8], vb[8];
        int bk[8];
#pragma unroll
        for (int k = 0; k < 8; ++k) {
            int i = i0 + k * 256 + t;
            if (i < nnz) {
                int r = rows[i], c = cols[i];
                pack[k] = ((unsigned int)r << 14) | (unsigned int)c;
                vb[k] = __float_as_uint(vals[i]);
                bk[k] = r >> 5;
                atomicAdd(&hist[bk[k]], 1);
            } else bk[k] = -1;
        }
        __syncthreads();
#pragma unroll
        for (int q = 0; q < 2; ++q) {
            int bin = t + q * 256;
            int h = hist[bin];
            base[bin] = (h > 0) ? atomicAdd(&gcursor[bin], h) : 0;
        }
        __syncthreads();
        hist[t] = 0; hist[t + 256] = 0;
        __syncthreads();
#pragma unroll
        for (int k = 0; k < 8; ++k) {
            if (bk[k] >= 0) {
                int p = base[bk[k]] + atomicAdd(&hist[bk[k]], 1);
                if (p < CAPB)
                    staging[(size_t)bk[k] * CAPB + p] = make_uint2(pack[k], vb[k]);
            }
        }
    }
}

// ---------------- phase B: within-bucket scatter to per-row bins ----------------
// 512 blocks x 512 threads. Binning uses ballot-based peer grouping: 5 ballots
// give each lane its same-key peer mask; one LDS atomic per peer group
// (leader), base broadcast via shfl -- no serialized conflicting DS atomics.
// Record (4 B): (col << 16) | fp16(val). Row implied by bin.

__global__ void __launch_bounds__(512)
bucket_scatter_kernel(const uint2* __restrict__ staging,
                      const int* __restrict__ gcursor,
                      unsigned int* __restrict__ edges, // [OUT][CAP]
                      int* __restrict__ counts) {
    __shared__ int lcnt[32];
    __shared__ unsigned int lbin[32 * CAP];   // 16 KB
    int b = blockIdx.x;
    int t = threadIdx.x;
    int lane = t & 63;
    if (t < 32) lcnt[t] = 0;
    __syncthreads();
    int n = gcursor[b];
    if (n > CAPB) n = CAPB;
    const unsigned long long* st = (const unsigned long long*)(staging + (size_t)b * CAPB);
    for (int i = t; i < n; i += 512) {
        unsigned long long v = __builtin_nontemporal_load(st + i);
        unsigned int key = (unsigned int)(v & 0xffffffffull);
        unsigned int vbits = (unsigned int)(v >> 32);
        int rl = (key >> 14) & 31;
        // peer mask over active lanes
        unsigned long long mask = __ballot(1);
#pragma unroll
        for (int bit = 0; bit < 5; ++bit) {
            unsigned long long bm = __ballot((rl >> bit) & 1);
            mask &= ((rl >> bit) & 1) ? bm : ~bm;
        }
        int rank = __popcll(mask & ((1ull << lane) - 1ull));
        int leader = __ffsll((long long)mask) - 1;
        int p0 = 0;
        if (rank == 0) p0 = atomicAdd(&lcnt[rl], __popcll(mask));
        p0 = __shfl(p0, leader, 64);
        int slot = p0 + rank;
        if (slot < CAP) {
            unsigned int col = key & 16383u;
            __half hv = __float2half(__uint_as_float(vbits));
            lbin[rl * CAP + slot] = (col << 16) | (unsigned int)__half_as_ushort(hv);
        }
    }
    __syncthreads();
    if (t < 32) {
        int c = lcnt[t];
        if (c > CAP) c = CAP;
        counts[b * 32 + t] = (c + 7) & ~7;
    }
    unsigned int* dst = edges + (size_t)b * 32 * CAP;
    for (int i4 = t; i4 < 32 * CAP / 4; i4 += 512) {
        int i = i4 * 4;
        int row = i >> 7;            // CAP = 128
        int slot = i & (CAP - 1);
        int c = lcnt[row];
        if (c > CAP) c = CAP;
        int lim = (c + 7) & ~7;
        if (slot < lim) {
            u32x4 v;
            v.x = (slot + 0 < c) ? lbin[i + 0] : 0u;
            v.y = (slot + 1 < c) ? lbin[i + 1] : 0u;
            v.z = (slot + 2 < c) ? lbin[i + 2] : 0u;
            v.w = (slot + 3 < c) ? lbin[i + 3] : 0u;
            __builtin_nontemporal_store(v, (u32x4*)(dst + i));
        }
    }
}

// ---------------- accumulate + direct transposed output ----------------
// 2048 blocks: rowgroup = blk>>1 (16 rows), h = blk&1 (round-robin XCD dispatch
// keeps one 4 MB xh half per XCD L2). Scalar edge lists with software-pipelined
// s_load prefetch; LDS slab; final out written directly (64 B line per store).

__global__ void accum_kernel(const unsigned int* __restrict__ xh0, // [2][IN][64] bf162
                             const unsigned int* __restrict__ edges, // [OUT][CAP]
                             const int*   __restrict__ counts,    // multiple of 8
                             const float* __restrict__ bias,
                             float* __restrict__ out) {            // [256][OUT]
    __shared__ float slab[128][17];     // [batch_in_half][row_local], pad 17
    int blk = blockIdx.x;
    int h = blk & 1;
    int o0 = (blk >> 1) * 16;
    int w = threadIdx.x >> 6;           // wave 0..3
    int lane = threadIdx.x & 63;
    const unsigned int* xh = xh0 + (size_t)h * IN_F * 64;
#pragma unroll
    for (int rr = 0; rr < 4; ++rr) {
        int rl = w * 4 + rr;
        int o = __builtin_amdgcn_readfirstlane(o0 + rl);
        int n = counts[o];              // uniform
        const u32x4* el4 = (const u32x4*)(edges + (size_t)o * CAP);
        float ax = 0.f, ay = 0.f;
        u32x4 ca = el4[0], cb = el4[1];
        for (int j = 0; j < n; j += 8) {
            u32x4 na = el4[(j >> 2) + 2];      // prefetch next chunk (<=32 B
            u32x4 nb = el4[(j >> 2) + 3];      //  overread stays in mapped ws)
            unsigned int e[8];
            e[0] = ca.x; e[1] = ca.y; e[2] = ca.z; e[3] = ca.w;
            e[4] = cb.x; e[5] = cb.y; e[6] = cb.z; e[7] = cb.w;
            unsigned int g[8];
#pragma unroll
            for (int k = 0; k < 8; ++k) {
                const unsigned int* p = xh + ((e[k] >> 16) << 6);  // scalar base
                g[k] = p[lane];                                     // vgpr offset
            }
#pragma unroll
            for (int k = 0; k < 8; ++k) {
                float v = __half2float(__ushort_as_half((unsigned short)(e[k] & 0xffffu)));
                ax += __uint_as_float(g[k] << 16) * v;
                ay += __uint_as_float(g[k] & 0xffff0000u) * v;
            }
            ca = na; cb = nb;
        }
        float bv = bias[o];
        slab[2 * lane + 0][rl] = ax + bv;   // batch 2t   of this half
        slab[2 * lane + 1][rl] = ay + bv;   // batch 2t+1
    }
    __syncthreads();
    // write phase: 512 float4 items (128 batches x 4 quarters), 2 per thread
#pragma unroll
    for (int it = 0; it < 2; ++it) {
        int item = threadIdx.x + it * 256;
        int bl = item >> 2;             // batch within half, 0..127
        int q = item & 3;               // quarter of 16 rows
        f32x4 v;
        v.x = slab[bl][q * 4 + 0];
        v.y = slab[bl][q * 4 + 1];
        v.z = slab[bl][q * 4 + 2];
        v.w = slab[bl][q * 4 + 3];
        __builtin_nontemporal_store(v,
            (f32x4*)(out + (size_t)(h * 128 + bl) * OUT_F + o0 + q * 4));
    }
}

extern "C" void kernel_launch(void* const* d_in, const int* in_sizes, int n_in,
                              void* d_out, int out_size, void* d_ws, size_t ws_size,
                              hipStream_t stream) {
    const float* x     = (const float*)d_in[0];
    const float* wvals = (const float*)d_in[1];
    const float* bias  = (const float*)d_in[2];
    const int*   rows  = (const int*)d_in[3];
    const int*   cols  = (const int*)d_in[4];
    float* out = (float*)d_out;
    int nnz = in_sizes[1];

    const size_t MB = 1024 * 1024;
    char* ws = (char*)d_ws;
    __hip_bfloat16* xTh = (__hip_bfloat16*)(ws);        // [0, 8 MB): [2][IN][128] bf16
    uint2* staging = (uint2*)(ws + 8 * MB);             // [8, 18.5 MB): [NBUCK][CAPB]
    unsigned int* edges = (unsigned int*)(ws + 22 * MB);// [22, 30 MB): [OUT][CAP] u32
    int*   gcursor = (int*)(ws + 30 * MB);              // 2 KB
    int*   counts  = (int*)(ws + 30 * MB + 4096);       // 64 KB

    (void)hipMemsetAsync(gcursor, 0, NBUCK * sizeof(int), stream);

    int npart = (nnz + EPB - 1) / EPB;
    prep_kernel<<<TBLK + npart, 256, 0, stream>>>(x, xTh, rows, cols, wvals, nnz,
                                                  gcursor, staging);
    bucket_scatter_kernel<<<NBUCK, 512, 0, stream>>>(staging, gcursor, edges, counts);
    accum_kernel<<<(OUT_F / 16) * 2, 256, 0, stream>>>((const unsigned int*)xTh, edges,
                                                       counts, bias, out);
}